// Round 1
// baseline (1013.500 us; speedup 1.0000x reference)
//
#include <hip/hip_runtime.h>
#include <cstdint>
#include <cstddef>

#define B_ROWS 65536
#define DMODEL 2048
#define NEXP 64
#define TOPK 8
#define BLK 128                 // threads per block == rows per block
#define DC 32                   // d-chunk staged in LDS
#define NCHUNK (DMODEL / DC)    // 64
#define LSTRIDE 33              // padded LDS stride: (33*lane+d)%32 conflict-free
#define NBLK (B_ROWS / BLK)     // 512
#define AUX_OFF ((size_t)B_ROWS * NEXP + (size_t)B_ROWS * TOPK)

__global__ __launch_bounds__(BLK) void router_main(
    const float* __restrict__ x, const float* __restrict__ W,
    const float* __restrict__ bias, float* __restrict__ out,
    float* __restrict__ ws)
{
  __shared__ float xs[BLK * LSTRIDE];
  __shared__ float redF[2 * NEXP];
  __shared__ float redP[2 * NEXP];

  const int tid = threadIdx.x;
  const int lane = tid & 63;
  const int wv = tid >> 6;
  const long row0 = (long)blockIdx.x * BLK;

  float acc[NEXP];
#pragma unroll
  for (int n = 0; n < NEXP; ++n) acc[n] = 0.f;

  const float4* xg = reinterpret_cast<const float4*>(x);
  float4 pf[8];
  // per-thread staging elements: flat float4 id f = tid + 128*i over the
  // [128 rows][8 float4] tile; r = f/8, q = f%8 -> 8 threads cover one
  // 128B row segment (coalesced).
#pragma unroll
  for (int i = 0; i < 8; ++i) {
    int f = tid + BLK * i;
    int r = f >> 3, q = f & 7;
    pf[i] = xg[(row0 + r) * (DMODEL / 4) + q];
  }

  for (int c = 0; c < NCHUNK; ++c) {
    // write prefetched chunk c to LDS
#pragma unroll
    for (int i = 0; i < 8; ++i) {
      int f = tid + BLK * i;
      int r = f >> 3, q = f & 7;
      float4 v = pf[i];
      float* dst = &xs[r * LSTRIDE + q * 4];
      dst[0] = v.x; dst[1] = v.y; dst[2] = v.z; dst[3] = v.w;
    }
    __syncthreads();
    // prefetch chunk c+1 (latency hidden under compute below)
    if (c + 1 < NCHUNK) {
#pragma unroll
      for (int i = 0; i < 8; ++i) {
        int f = tid + BLK * i;
        int r = f >> 3, q = f & 7;
        pf[i] = xg[(row0 + r) * (DMODEL / 4) + (c + 1) * (DC / 4) + q];
      }
    }
    // compute: thread owns one row; W accesses are wave-uniform -> s_load
    const float* wb = W + (size_t)c * DC * NEXP;
#pragma unroll 4
    for (int dd = 0; dd < DC; ++dd) {
      float xv = xs[tid * LSTRIDE + dd];
      const float* wr = wb + dd * NEXP;
#pragma unroll
      for (int n = 0; n < NEXP; ++n)
        acc[n] = fmaf(xv, wr[n], acc[n]);
    }
    __syncthreads();
  }

  // ---------------- epilogue (per thread = per row) ----------------
  // top-8 by biased logits; strict > keeps lowest index on ties (jax top_k)
  unsigned long long sel = 0ull;
  int idx[TOPK];
  float selu[TOPK];
#pragma unroll
  for (int k = 0; k < TOPK; ++k) {
    float best = -INFINITY, bestu = 0.f;
    int bi = 0;
#pragma unroll
    for (int n = 0; n < NEXP; ++n) {
      float vb = acc[n] + bias[n];
      bool taken = (sel >> n) & 1ull;
      vb = taken ? -INFINITY : vb;
      if (vb > best) { best = vb; bestu = acc[n]; bi = n; }
    }
    sel |= 1ull << bi;
    idx[k] = bi;
    selu[k] = bestu;
  }

  // softmax over selected UNbiased logits
  float mx = selu[0];
#pragma unroll
  for (int k = 1; k < TOPK; ++k) mx = fmaxf(mx, selu[k]);
  float g[TOPK]; float gs = 0.f;
#pragma unroll
  for (int k = 0; k < TOPK; ++k) { g[k] = __expf(selu[k] - mx); gs += g[k]; }
  float ginv = 1.f / gs;

  // scatter gates row (all 64 written; static indexing only)
  float* grow = out + (row0 + tid) * NEXP;
#pragma unroll
  for (int n = 0; n < NEXP; ++n) {
    float gv = 0.f;
#pragma unroll
    for (int k = 0; k < TOPK; ++k) gv = (idx[k] == n) ? g[k] * ginv : gv;
    grow[n] = gv;
  }

  // indices as float32
  float* irow = out + (size_t)B_ROWS * NEXP + (row0 + tid) * TOPK;
#pragma unroll
  for (int k = 0; k < TOPK; ++k) irow[k] = (float)idx[k];

  // full softmax over all 64 logits for P_i
  float m2 = -INFINITY;
#pragma unroll
  for (int n = 0; n < NEXP; ++n) m2 = fmaxf(m2, acc[n]);
  float s2 = 0.f;
#pragma unroll
  for (int n = 0; n < NEXP; ++n) s2 += __expf(acc[n] - m2);
  float pinv = 1.f / s2;

  // per-expert cross-lane reduction: after butterfly, lane n keeps expert n
  float myP = 0.f, myF = 0.f;
#pragma unroll
  for (int n = 0; n < NEXP; ++n) {
    float v = __expf(acc[n] - m2) * pinv;
    v += __shfl_xor(v, 1);
    v += __shfl_xor(v, 2);
    v += __shfl_xor(v, 4);
    v += __shfl_xor(v, 8);
    v += __shfl_xor(v, 16);
    v += __shfl_xor(v, 32);
    unsigned long long b = __ballot((sel >> n) & 1ull);
    if (lane == n) { myP = v; myF = (float)__popcll(b); }
  }

  redP[wv * NEXP + lane] = myP;
  redF[wv * NEXP + lane] = myF;
  __syncthreads();
  if (tid < NEXP) {
    float F = redF[tid] + redF[NEXP + tid];
    float P = redP[tid] + redP[NEXP + tid];
    ws[(size_t)blockIdx.x * (2 * NEXP) + tid] = F;
    ws[(size_t)blockIdx.x * (2 * NEXP) + NEXP + tid] = P;
  }
}

// deterministic final reduction over the 512 block partials
__global__ __launch_bounds__(256) void router_aux(
    const float* __restrict__ ws, float* __restrict__ out)
{
  __shared__ float sf[4][NEXP];
  __shared__ float sp[4][NEXP];
  int t = threadIdx.x;
  int n = t & 63, part = t >> 6;
  float f = 0.f, p = 0.f;
#pragma unroll 8
  for (int b = part; b < NBLK; b += 4) {
    f += ws[(size_t)b * (2 * NEXP) + n];
    p += ws[(size_t)b * (2 * NEXP) + NEXP + n];
  }
  sf[part][n] = f;
  sp[part][n] = p;
  __syncthreads();
  if (t < NEXP) {
    float F = sf[0][t] + sf[1][t] + sf[2][t] + sf[3][t];
    float P = sp[0][t] + sp[1][t] + sp[2][t] + sp[3][t];
    float v = F * P;
    v += __shfl_xor(v, 1);
    v += __shfl_xor(v, 2);
    v += __shfl_xor(v, 4);
    v += __shfl_xor(v, 8);
    v += __shfl_xor(v, 16);
    v += __shfl_xor(v, 32);
    if (t == 0)
      out[AUX_OFF] = 0.01f * 64.f * v / (4294967296.0f /* 65536^2 */);
  }
}

extern "C" void kernel_launch(void* const* d_in, const int* in_sizes, int n_in,
                              void* d_out, int out_size, void* d_ws, size_t ws_size,
                              hipStream_t stream) {
  const float* x = (const float*)d_in[0];
  const float* W = (const float*)d_in[1];
  const float* bias = (const float*)d_in[2];
  float* out = (float*)d_out;
  float* ws = (float*)d_ws;
  router_main<<<NBLK, BLK, 0, stream>>>(x, W, bias, out, ws);
  router_aux<<<1, 256, 0, stream>>>(ws, out);
}

// Round 2
// 812.803 us; speedup vs baseline: 1.2469x; 1.2469x over previous
//
#include <hip/hip_runtime.h>
#include <cstdint>
#include <cstddef>

#define B_ROWS 65536
#define DMODEL 2048
#define NEXP 64
#define TOPK 8
#define ROWS_PER_BLK 128
#define NPART 4
#define PART_D (DMODEL / NPART)       // 512
#define DC 32                         // dd per staged chunk
#define NCHUNK (PART_D / DC)          // 16
#define THREADS 512                   // 8 waves
#define XS_STRIDE 33                  // (lane+dd)%32 -> 2-way max (free)
#define ACC_STRIDE 66                 // (2*lane+n)%32 -> 2-way max (free)
#define NBLK (B_ROWS / ROWS_PER_BLK)  // 512
#define AUX_OFF ((size_t)B_ROWS * NEXP + (size_t)B_ROWS * TOPK)

__global__ __launch_bounds__(THREADS, 4) void router_main(
    const float* __restrict__ x, const float* __restrict__ W,
    const float* __restrict__ bias, float* __restrict__ out,
    float* __restrict__ ws)
{
  // union: per-wave x staging (8*64*33 = 16896 floats) overlaps the
  // post-loop accumulator buffer (128*66 = 8448 floats); barrier separates.
  __shared__ float lds[8 * 64 * XS_STRIDE];
  __shared__ float redF[2 * NEXP];
  __shared__ float redP[2 * NEXP];

  const int tid = threadIdx.x;
  const int lane = tid & 63;
  const int w = tid >> 6;
  // force wave-uniform scalars so W indexing stays on the scalar pipe
  const int rg = __builtin_amdgcn_readfirstlane(w & 1);   // row group 0/1
  const int p  = __builtin_amdgcn_readfirstlane(w >> 1);  // D-part 0..3
  const long rowbase = (long)blockIdx.x * ROWS_PER_BLK + (long)rg * 64;

  float* xs   = &lds[w * (64 * XS_STRIDE)];
  float* accb = lds;  // [128][ACC_STRIDE]

  float acc[NEXP];
#pragma unroll
  for (int n = 0; n < NEXP; ++n) acc[n] = 0.f;

  const float4* xg = reinterpret_cast<const float4*>(x);
  float4 pf[8];

  // stage element f = lane + 64*i over [64 rows][8 float4]: r=f/8, q=f%8
  // -> 8 consecutive lanes read one 128B row segment (coalesced).
#pragma unroll
  for (int i = 0; i < 8; ++i) {
    int f = lane + 64 * i;
    int r = f >> 3, q = f & 7;
    pf[i] = xg[(rowbase + r) * (DMODEL / 4) + (size_t)p * (PART_D / 4) + q];
  }

  for (int c = 0; c < NCHUNK; ++c) {
    // write prefetched chunk to this wave's private LDS area (no barrier)
#pragma unroll
    for (int i = 0; i < 8; ++i) {
      int f = lane + 64 * i;
      int r = f >> 3, q = f & 7;
      float* dst = &xs[r * XS_STRIDE + q * 4];
      dst[0] = pf[i].x; dst[1] = pf[i].y; dst[2] = pf[i].z; dst[3] = pf[i].w;
    }
    // prefetch next chunk (latency hides under FMAs below)
    if (c + 1 < NCHUNK) {
#pragma unroll
      for (int i = 0; i < 8; ++i) {
        int f = lane + 64 * i;
        int r = f >> 3, q = f & 7;
        pf[i] = xg[(rowbase + r) * (DMODEL / 4) + (size_t)p * (PART_D / 4)
                   + (c + 1) * (DC / 4) + q];
      }
    }
    const float* wb = W + (size_t)(p * PART_D + c * DC) * NEXP;
#pragma unroll 4
    for (int dd = 0; dd < DC; ++dd) {
      float xv = xs[lane * XS_STRIDE + dd];
      const float* wr = wb + dd * NEXP;   // wave-uniform -> s_load
#pragma unroll
      for (int n = 0; n < NEXP; ++n)
        acc[n] = fmaf(xv, wr[n], acc[n]);
    }
  }

  // ---- combine the 4 D-part partials per row via LDS rounds ----
  __syncthreads();   // staging areas die; accb becomes live
  if (p == 0) {
#pragma unroll
    for (int n = 0; n < NEXP; ++n)
      accb[(rg * 64 + lane) * ACC_STRIDE + n] = acc[n];
  }
  __syncthreads();
#pragma unroll
  for (int pp = 1; pp < NPART; ++pp) {
    if (p == pp) {
#pragma unroll
      for (int n = 0; n < NEXP; ++n)
        accb[(rg * 64 + lane) * ACC_STRIDE + n] += acc[n];
    }
    __syncthreads();
  }

  // ---------------- epilogue: waves 0-1, lane = row ----------------
  if (w < 2) {
    const int row = w * 64 + lane;
    float a[NEXP];
#pragma unroll
    for (int n = 0; n < NEXP; ++n) a[n] = accb[row * ACC_STRIDE + n];

    // top-8 by biased logits; strict > keeps lowest index on ties
    unsigned long long sel = 0ull;
    int idx[TOPK];
    float selu[TOPK];
#pragma unroll
    for (int k = 0; k < TOPK; ++k) {
      float best = -INFINITY, bestu = 0.f;
      int bi = 0;
#pragma unroll
      for (int n = 0; n < NEXP; ++n) {
        float vb = a[n] + bias[n];
        bool taken = (sel >> n) & 1ull;
        vb = taken ? -INFINITY : vb;
        if (vb > best) { best = vb; bestu = a[n]; bi = n; }
      }
      sel |= 1ull << bi;
      idx[k] = bi;
      selu[k] = bestu;
    }

    float mx = selu[0];
#pragma unroll
    for (int k = 1; k < TOPK; ++k) mx = fmaxf(mx, selu[k]);
    float g[TOPK]; float gs = 0.f;
#pragma unroll
    for (int k = 0; k < TOPK; ++k) { g[k] = __expf(selu[k] - mx); gs += g[k]; }
    float ginv = 1.f / gs;

    float* grow = out + (size_t)((long)blockIdx.x * ROWS_PER_BLK + row) * NEXP;
#pragma unroll
    for (int n = 0; n < NEXP; ++n) {
      float gv = 0.f;
#pragma unroll
      for (int k = 0; k < TOPK; ++k) gv = (idx[k] == n) ? g[k] * ginv : gv;
      grow[n] = gv;
    }

    float* irow = out + (size_t)B_ROWS * NEXP
                + (size_t)((long)blockIdx.x * ROWS_PER_BLK + row) * TOPK;
#pragma unroll
    for (int k = 0; k < TOPK; ++k) irow[k] = (float)idx[k];

    // full softmax over all 64 logits for P_i
    float m2 = -INFINITY;
#pragma unroll
    for (int n = 0; n < NEXP; ++n) m2 = fmaxf(m2, a[n]);
    float s2 = 0.f;
#pragma unroll
    for (int n = 0; n < NEXP; ++n) s2 += __expf(a[n] - m2);
    float pinv = 1.f / s2;

    float myP = 0.f, myF = 0.f;
#pragma unroll
    for (int n = 0; n < NEXP; ++n) {
      float v = __expf(a[n] - m2) * pinv;
      v += __shfl_xor(v, 1);
      v += __shfl_xor(v, 2);
      v += __shfl_xor(v, 4);
      v += __shfl_xor(v, 8);
      v += __shfl_xor(v, 16);
      v += __shfl_xor(v, 32);
      unsigned long long b = __ballot((sel >> n) & 1ull);
      if (lane == n) { myP = v; myF = (float)__popcll(b); }
    }
    redP[w * NEXP + lane] = myP;
    redF[w * NEXP + lane] = myF;
  }

  __syncthreads();
  if (tid < NEXP) {
    float F = redF[tid] + redF[NEXP + tid];
    float P = redP[tid] + redP[NEXP + tid];
    ws[(size_t)blockIdx.x * (2 * NEXP) + tid] = F;
    ws[(size_t)blockIdx.x * (2 * NEXP) + NEXP + tid] = P;
  }
}

// deterministic final reduction over the 512 block partials
__global__ __launch_bounds__(256) void router_aux(
    const float* __restrict__ ws, float* __restrict__ out)
{
  __shared__ float sf[4][NEXP];
  __shared__ float sp[4][NEXP];
  int t = threadIdx.x;
  int n = t & 63, part = t >> 6;
  float f = 0.f, p = 0.f;
#pragma unroll 8
  for (int b = part; b < NBLK; b += 4) {
    f += ws[(size_t)b * (2 * NEXP) + n];
    p += ws[(size_t)b * (2 * NEXP) + NEXP + n];
  }
  sf[part][n] = f;
  sp[part][n] = p;
  __syncthreads();
  if (t < NEXP) {
    float F = sf[0][t] + sf[1][t] + sf[2][t] + sf[3][t];
    float P = sp[0][t] + sp[1][t] + sp[2][t] + sp[3][t];
    float v = F * P;
    v += __shfl_xor(v, 1);
    v += __shfl_xor(v, 2);
    v += __shfl_xor(v, 4);
    v += __shfl_xor(v, 8);
    v += __shfl_xor(v, 16);
    v += __shfl_xor(v, 32);
    if (t == 0)
      out[AUX_OFF] = 0.01f * 64.f * v / (4294967296.0f /* 65536^2 */);
  }
}

extern "C" void kernel_launch(void* const* d_in, const int* in_sizes, int n_in,
                              void* d_out, int out_size, void* d_ws, size_t ws_size,
                              hipStream_t stream) {
  const float* x = (const float*)d_in[0];
  const float* W = (const float*)d_in[1];
  const float* bias = (const float*)d_in[2];
  float* out = (float*)d_out;
  float* ws = (float*)d_ws;
  router_main<<<NBLK, THREADS, 0, stream>>>(x, W, bias, out, ws);
  router_aux<<<1, 256, 0, stream>>>(ws, out);
}

// Round 3
// 544.488 us; speedup vs baseline: 1.8614x; 1.4928x over previous
//
#include <hip/hip_runtime.h>
#include <cstdint>
#include <cstddef>

#define B_ROWS 65536
#define DMODEL 2048
#define NEXP 64
#define TOPK 8
#define ROWS_PER_BLK 128
#define DC 32                          // D-chunk per staging round
#define NCHUNK (DMODEL / DC)           // 64
#define THREADS 512                    // 8 waves
#define NWAVE 8
#define RPW 16                         // rows per wave
#define ACC_STRIDE 66                  // (2*lane+n)%32 -> 2-way (free)
#define NBLK (B_ROWS / ROWS_PER_BLK)   // 512
#define AUX_OFF ((size_t)B_ROWS * NEXP + (size_t)B_ROWS * TOPK)

#define GLOAD_LDS16(g, l)                                                  \
  __builtin_amdgcn_global_load_lds(                                       \
      (const __attribute__((address_space(1))) void*)(g),                 \
      (__attribute__((address_space(3))) void*)(l), 16, 0, 0)

__global__ __launch_bounds__(THREADS, 4) void router_main(
    const float* __restrict__ x, const float* __restrict__ W,
    const float* __restrict__ bias, float* __restrict__ out,
    float* __restrict__ ws)
{
  // union: staging {xs [128][32] = 16KB, wsW [32][64] = 8KB} then
  // accb [128][66] = 33792B. Barrier separates lifetimes.
  __shared__ float lds[ROWS_PER_BLK * ACC_STRIDE];
  __shared__ float redF[2 * NEXP];
  __shared__ float redP[2 * NEXP];

  float* xs  = lds;                          // 4096 floats
  float* wsW = lds + ROWS_PER_BLK * DC;      // 2048 floats

  const int tid = threadIdx.x;
  const int lane = tid & 63;
  const int w = tid >> 6;
  const size_t row0 = (size_t)blockIdx.x * ROWS_PER_BLK;

  float acc[RPW];
#pragma unroll
  for (int r = 0; r < RPW; ++r) acc[r] = 0.f;

  // per-lane source offsets for staging (constant across chunks)
  const int xr = lane >> 3;            // 0..7 row within 8-row group
  const int xq = (lane & 7) * 4;       // dword col within 32
  const float* xbase0 = x + (row0 + (size_t)w * RPW + xr) * DMODEL + xq;
  const float* xbase1 = xbase0 + 8 * DMODEL;
  const float* wbase  = W + (size_t)w * 256 + (size_t)lane * 4;

  for (int c = 0; c < NCHUNK; ++c) {
    // stage: wave w loads its own 16 x-rows (2 instr) + 1KB of W (1 instr)
    GLOAD_LDS16(xbase0 + c * DC, xs + (w * RPW) * DC);
    GLOAD_LDS16(xbase1 + c * DC, xs + (w * RPW + 8) * DC);
    GLOAD_LDS16(wbase + (size_t)c * DC * NEXP, wsW + w * 256);
    __syncthreads();   // drains vmcnt -> LDS valid

#pragma unroll
    for (int d4 = 0; d4 < DC / 4; ++d4) {
      float w0 = wsW[(d4 * 4 + 0) * NEXP + lane];
      float w1 = wsW[(d4 * 4 + 1) * NEXP + lane];
      float w2 = wsW[(d4 * 4 + 2) * NEXP + lane];
      float w3 = wsW[(d4 * 4 + 3) * NEXP + lane];
#pragma unroll
      for (int r = 0; r < RPW; ++r) {
        float4 xv = *(const float4*)&xs[(w * RPW + r) * DC + d4 * 4];
        acc[r] = fmaf(xv.x, w0, acc[r]);
        acc[r] = fmaf(xv.y, w1, acc[r]);
        acc[r] = fmaf(xv.z, w2, acc[r]);
        acc[r] = fmaf(xv.w, w3, acc[r]);
      }
    }
    __syncthreads();   // staging buffers free to overwrite
  }

  // transpose acc -> accb[row][expert] (writes lane-consecutive: no conflict)
#pragma unroll
  for (int r = 0; r < RPW; ++r)
    lds[(w * RPW + r) * ACC_STRIDE + lane] = acc[r];
  __syncthreads();

  // ---------------- epilogue: waves 0-1, lane = row ----------------
  if (w < 2) {
    const int row = w * 64 + lane;
    float a[NEXP];
#pragma unroll
    for (int n = 0; n < NEXP; ++n) a[n] = lds[row * ACC_STRIDE + n];

    // top-8 by biased logits; strict > keeps lowest index on ties
    unsigned long long sel = 0ull;
    int idx[TOPK];
    float selu[TOPK];
#pragma unroll
    for (int k = 0; k < TOPK; ++k) {
      float best = -INFINITY, bestu = 0.f;
      int bi = 0;
#pragma unroll
      for (int n = 0; n < NEXP; ++n) {
        float vb = a[n] + bias[n];
        bool taken = (sel >> n) & 1ull;
        vb = taken ? -INFINITY : vb;
        if (vb > best) { best = vb; bestu = a[n]; bi = n; }
      }
      sel |= 1ull << bi;
      idx[k] = bi;
      selu[k] = bestu;
    }

    float mx = selu[0];
#pragma unroll
    for (int k = 1; k < TOPK; ++k) mx = fmaxf(mx, selu[k]);
    float g[TOPK]; float gs = 0.f;
#pragma unroll
    for (int k = 0; k < TOPK; ++k) { g[k] = __expf(selu[k] - mx); gs += g[k]; }
    float ginv = 1.f / gs;

    float* grow = out + (row0 + row) * NEXP;
#pragma unroll
    for (int n = 0; n < NEXP; ++n) {
      float gv = 0.f;
#pragma unroll
      for (int k = 0; k < TOPK; ++k) gv = (idx[k] == n) ? g[k] * ginv : gv;
      grow[n] = gv;
    }

    float* irow = out + (size_t)B_ROWS * NEXP + (row0 + row) * TOPK;
#pragma unroll
    for (int k = 0; k < TOPK; ++k) irow[k] = (float)idx[k];

    // full softmax over all 64 logits for P_i
    float m2 = -INFINITY;
#pragma unroll
    for (int n = 0; n < NEXP; ++n) m2 = fmaxf(m2, a[n]);
    float s2 = 0.f;
#pragma unroll
    for (int n = 0; n < NEXP; ++n) s2 += __expf(a[n] - m2);
    float pinv = 1.f / s2;

    float myP = 0.f, myF = 0.f;
#pragma unroll
    for (int n = 0; n < NEXP; ++n) {
      float v = __expf(a[n] - m2) * pinv;
      v += __shfl_xor(v, 1);
      v += __shfl_xor(v, 2);
      v += __shfl_xor(v, 4);
      v += __shfl_xor(v, 8);
      v += __shfl_xor(v, 16);
      v += __shfl_xor(v, 32);
      unsigned long long b = __ballot((sel >> n) & 1ull);
      if (lane == n) { myP = v; myF = (float)__popcll(b); }
    }
    redP[w * NEXP + lane] = myP;
    redF[w * NEXP + lane] = myF;
  }

  __syncthreads();
  if (tid < NEXP) {
    float F = redF[tid] + redF[NEXP + tid];
    float P = redP[tid] + redP[NEXP + tid];
    ws[(size_t)blockIdx.x * (2 * NEXP) + tid] = F;
    ws[(size_t)blockIdx.x * (2 * NEXP) + NEXP + tid] = P;
  }
}

// deterministic final reduction over the 512 block partials
__global__ __launch_bounds__(256) void router_aux(
    const float* __restrict__ ws, float* __restrict__ out)
{
  __shared__ float sf[4][NEXP];
  __shared__ float sp[4][NEXP];
  int t = threadIdx.x;
  int n = t & 63, part = t >> 6;
  float f = 0.f, p = 0.f;
#pragma unroll 8
  for (int b = part; b < NBLK; b += 4) {
    f += ws[(size_t)b * (2 * NEXP) + n];
    p += ws[(size_t)b * (2 * NEXP) + NEXP + n];
  }
  sf[part][n] = f;
  sp[part][n] = p;
  __syncthreads();
  if (t < NEXP) {
    float F = sf[0][t] + sf[1][t] + sf[2][t] + sf[3][t];
    float P = sp[0][t] + sp[1][t] + sp[2][t] + sp[3][t];
    float v = F * P;
    v += __shfl_xor(v, 1);
    v += __shfl_xor(v, 2);
    v += __shfl_xor(v, 4);
    v += __shfl_xor(v, 8);
    v += __shfl_xor(v, 16);
    v += __shfl_xor(v, 32);
    if (t == 0)
      out[AUX_OFF] = 0.01f * 64.f * v / (4294967296.0f /* 65536^2 */);
  }
}

extern "C" void kernel_launch(void* const* d_in, const int* in_sizes, int n_in,
                              void* d_out, int out_size, void* d_ws, size_t ws_size,
                              hipStream_t stream) {
  const float* x = (const float*)d_in[0];
  const float* W = (const float*)d_in[1];
  const float* bias = (const float*)d_in[2];
  float* out = (float*)d_out;
  float* ws = (float*)d_ws;
  router_main<<<NBLK, THREADS, 0, stream>>>(x, W, bias, out, ws);
  router_aux<<<1, 256, 0, stream>>>(ws, out);
}